// Round 6
// baseline (173.406 us; speedup 1.0000x reference)
//
#include <hip/hip_runtime.h>

// Fused kernelized attention w/ Toeplitz topological mask, MI355X gfx950.
// B=8 H=12 L=577 (24x24 grid + CLS) D=64, fp32 I/O (runtime-probed vs bf16).
//
// out[b,q,h,:] = sum_k p(q,k) v[k,:] / sum_k p(q,k)
//   p = (relu(q)/8+eps)·(relu(k)+eps) * |mask(h,q,k)| + eps
//
// R6: BARRIER-FREE main kernel. K'/V^T/M are pre-packed in d_ws by one prep
// kernel; the main kernel reads K' and V^T MFMA fragments DIRECTLY from
// global (L2-resident working set, 16-row x 64B segments per b128) and M as
// coalesced b64 register loads. Only the P matrix round-trips through a
// wave-private LDS tile (same-wave lgkmcnt ordering). No __syncthreads in
// the whole body -> waves stream independently; no vmcnt(0) barrier drains.

#define Lq 577
#define NH 12
#define NB 8
#define DD 64
#define PAR 2304
#define EPSf 1e-8f

// workspace layout (bytes)
#define VT_OFF 7090176ull     // K' = 3,545,088 elem * 2B  [b,k,h,d]
#define M2_OFF 14954496ull    // + V^T = 8*12*64*640*2 = 7,864,320
                              // + M2  = 12*40*10*4*64*4*2 = 9,830,400 (24.8 MB)

// prep grid sections
#define KBLK 1731             // K': 1731*256*8 = 3,545,088 elems
#define VBLK 960              // V^T: 10 kt x 12 h x 8 b
#define MBLK 480              // M2: 40 qg x 12 h

typedef __attribute__((ext_vector_type(4))) float f32x4;
typedef __attribute__((ext_vector_type(8))) short s16x8;

__device__ __forceinline__ float bflo(unsigned int u) {
    return __builtin_bit_cast(float, u << 16);
}
__device__ __forceinline__ float bfhi(unsigned int u) {
    return __builtin_bit_cast(float, u & 0xffff0000u);
}
// float -> bf16 round-to-nearest-even
__device__ __forceinline__ unsigned int f2bf(float f) {
    unsigned int x = __builtin_bit_cast(unsigned int, f);
    return (x + 0x7fffu + ((x >> 16) & 1u)) >> 16;
}
__device__ __forceinline__ int imin(int a, int b) { return a < b ? a : b; }

// per-wave dtype probe: fp32 N(0,1) lands in (2^-12, 64); bf16-pair
// reinterpretation lands at ~2^+-100 / denormal. Works for partial waves.
__device__ __forceinline__ bool probe_f32(const void* Qg) {
    float x = fabsf(((const float*)Qg)[threadIdx.x]);
    unsigned long long hit = __ballot(x > 2.44140625e-4f && x < 64.0f);
    unsigned long long act = __ballot(1);
    return 2 * __popcll(hit) >= __popcll(act);
}

// 8 consecutive elements -> float, dtype-templated
template <bool F32>
__device__ __forceinline__ void load8f(const void* G, size_t eidx, float* o) {
    if constexpr (F32) {
        const float* p = (const float*)G + eidx;
        float4 a = *(const float4*)p;
        float4 b = *(const float4*)(p + 4);
        o[0] = a.x; o[1] = a.y; o[2] = a.z; o[3] = a.w;
        o[4] = b.x; o[5] = b.y; o[6] = b.z; o[7] = b.w;
    } else {
        const unsigned short* p = (const unsigned short*)G + eidx;
        uint4 a = *(const uint4*)p;
        unsigned int u[4] = {a.x, a.y, a.z, a.w};
#pragma unroll
        for (int j = 0; j < 4; ++j) {
            o[2 * j]     = bflo(u[j]);
            o[2 * j + 1] = bfhi(u[j]);
        }
    }
}

// ---------------- fused prep: K' | V^T | M2 by grid section
template <bool F32>
__device__ void prep_k_body(const void* Kg, unsigned short* Kp, int bx) {
    size_t i8 = ((size_t)bx * 256 + threadIdx.x) * 8;
    float f[8];
    load8f<F32>(Kg, i8, f);
    unsigned int o[4];
#pragma unroll
    for (int j = 0; j < 4; ++j) {
        unsigned int lo = f2bf(fmaxf(f[2 * j], 0.0f) + EPSf);
        unsigned int hi = f2bf(fmaxf(f[2 * j + 1], 0.0f) + EPSf);
        o[j] = lo | (hi << 16);
    }
    *(uint4*)(Kp + i8) = make_uint4(o[0], o[1], o[2], o[3]);
}

template <bool F32>
__device__ void prep_vt_body(const void* Vg, unsigned short* Vt,
                             unsigned short* s, int id) {
    const int t  = threadIdx.x;
    const int kt = id % 10;
    const int h  = (id / 10) % NH;
    const int b  = id / 120;
    {
        int kl  = t >> 2;              // 0..63
        int dch = (t & 3) * 16;
        int k   = kt * 64 + kl;
        unsigned int pk[8] = {};
        if (k <= 576) {
            float f[16];
            size_t base = ((size_t)((b * Lq + k) * NH + h)) * DD + dch;
            load8f<F32>(Vg, base, f);
            load8f<F32>(Vg, base + 8, f + 8);
#pragma unroll
            for (int j = 0; j < 8; ++j) {
                float a0 = f[2 * j], a1 = f[2 * j + 1];
                a0 = (a0 == a0) ? a0 : 0.0f;
                a1 = (a1 == a1) ? a1 : 0.0f;
                pk[j] = f2bf(a0) | (f2bf(a1) << 16);
            }
        }
#pragma unroll
        for (int j = 0; j < 8; ++j)
            *(unsigned int*)&s[kl * 72 + dch + 2 * j] = pk[j];
    }
    __syncthreads();
    {
        int d   = t >> 2;
        int kch = (t & 3) * 16;
        unsigned int o[8];
#pragma unroll
        for (int j = 0; j < 8; ++j) {
            unsigned short v0 = s[(kch + 2 * j) * 72 + d];
            unsigned short v1 = s[(kch + 2 * j + 1) * 72 + d];
            o[j] = (unsigned int)v0 | ((unsigned int)v1 << 16);
        }
        size_t base = ((size_t)((b * NH + h) * 64 + d)) * 640 + kt * 64 + kch;
        *(uint4*)(Vt + base)     = make_uint4(o[0], o[1], o[2], o[3]);
        *(uint4*)(Vt + base + 8) = make_uint4(o[4], o[5], o[6], o[7]);
    }
}

// M2[h][qg][kt][cf][lane] quads of bf16: lane (lm=lane&15, g=lane>>4) holds
// |mask| for q = qg*16+lm, k = kt*64 + cf*16 + g*4 + {0..3}
template <bool F32>
__device__ void prep_m2_body(const void* Tg, unsigned short* M2, int id) {
    const int qg = id % 40;
    const int h  = id / 40;
    const int t    = threadIdx.x;
    const int cf   = t >> 6;
    const int lane = t & 63;
    const int lm   = lane & 15;
    const int g    = lane >> 4;
    const int q    = qg * 16 + lm;
    const bool qok = q < Lq;
    int cq = 0;
    if (qok && q > 0) {
        int qq = q - 1;
        int qi = (qq * 2731) >> 16;       // floor(qq/24)
        cq = qq + 24 * qi + 1176;
    }
    for (int kt = 0; kt < 10; ++kt) {
        unsigned int hv[4];
#pragma unroll
        for (int e = 0; e < 4; ++e) {
            int k = kt * 64 + cf * 16 + g * 4 + e;
            float m;
            if (!qok || k > 576) m = 0.0f;
            else if (k == 0 || q == 0) m = 1.0f;
            else {
                int kk = k - 1;
                int ki = (kk * 2731) >> 16;
                int idx = cq - (kk + 24 * ki);
                float pv = F32 ? ((const float*)Tg)[h * PAR + idx]
                               : bflo((unsigned int)((const unsigned short*)Tg)[h * PAR + idx]);
                m = fabsf(pv);
                m = (m == m) ? m : 0.0f;
            }
            hv[e] = f2bf(m);
        }
        size_t base = ((size_t)(((h * 40 + qg) * 10 + kt) * 4 + cf) * 64 + lane) * 4;
        *(uint2*)(M2 + base) = make_uint2(hv[0] | (hv[1] << 16), hv[2] | (hv[3] << 16));
    }
}

__global__ __launch_bounds__(256)
void prep_all(const void* __restrict__ Qg, const void* __restrict__ Kg,
              const void* __restrict__ Vg, const void* __restrict__ Tg,
              unsigned short* __restrict__ Kp, unsigned short* __restrict__ Vt,
              unsigned short* __restrict__ M2) {
    __shared__ unsigned short s[64 * 72];
    bool f32 = probe_f32(Qg);
    int bx = blockIdx.x;
    if (bx < KBLK) {
        if (f32) prep_k_body<true>(Kg, Kp, bx);
        else     prep_k_body<false>(Kg, Kp, bx);
    } else if (bx < KBLK + VBLK) {
        if (f32) prep_vt_body<true>(Vg, Vt, s, bx - KBLK);
        else     prep_vt_body<false>(Vg, Vt, s, bx - KBLK);
    } else {
        if (f32) prep_m2_body<true>(Tg, M2, bx - KBLK - VBLK);
        else     prep_m2_body<false>(Tg, M2, bx - KBLK - VBLK);
    }
}

// ---------------- main kernel (no barriers)
template <bool F32>
__device__ void attn_body(const void* __restrict__ Qg,
                          const unsigned short* __restrict__ Kp,
                          const unsigned short* __restrict__ Vt,
                          const unsigned short* __restrict__ M2,
                          void* __restrict__ Og,
                          unsigned short* s_p_all) {
    const int tid  = threadIdx.x;
    const int w    = tid >> 6;
    const int lane = tid & 63;
    const int g    = lane >> 4;   // quad
    const int lm   = lane & 15;

    // XCD swizzle: blocks sharing (b,h) are 96 apart (96 % 8 == 0 -> same XCD)
    const int bid = blockIdx.x;
    const int qt  = bid / 96;     // q tile (64 rows), 0..9
    const int bh  = bid - qt * 96;
    const int h   = bh % NH;
    const int b   = bh / NH;

    unsigned short* s_pw = s_p_all + w * 16 * 72;   // wave-private P tile [16][72]

    const int q0w = qt * 64 + w * 16;   // wave's first q row
    const int qg  = qt * 4 + w;         // 16-q group index for M2

    // ---- Q B-frags in registers: lane holds Q[q0w+lm][ds*32+g*8+j]
    const int q  = q0w + lm;
    const int qc = imin(q, Lq - 1);
    s16x8 a_q[2];
    {
        size_t rbase = ((size_t)((b * Lq + qc) * NH + h)) * DD;
#pragma unroll
        for (int ds = 0; ds < 2; ++ds) {
            float f[8];
            load8f<F32>(Qg, rbase + ds * 32 + g * 8, f);
            s16x8 a;
#pragma unroll
            for (int j = 0; j < 8; ++j) {
                float v = fmaf(fmaxf(f[j], 0.0f), 0.125f, EPSf);  // relu/8+eps
                a[j] = (short)f2bf(v);
            }
            a_q[ds] = a;
        }
    }

    // ---- global fragment base pointers
    const unsigned short* KpBH = Kp + (size_t)b * (Lq * NH * DD) + h * DD + g * 8;  // +k*768
    const unsigned short* VtD[4];
#pragma unroll
    for (int df = 0; df < 4; ++df)
        VtD[df] = Vt + ((size_t)(b * NH + h) * 64 + (df * 16 + lm)) * 640 + g * 8;
    const unsigned short* Mw = M2 + (size_t)(h * 40 + qg) * 10240 + lane * 4;  // +t*1024+cf*256

    f32x4 o_acc[4] = {};   // [df] C-frags: rows q_local=g*4+r, cols d=df*16+lm
    float rs = 0.0f;       // per-lane partial row sum for q (this quad's k subset)

#pragma unroll 1
    for (int t = 0; t < 10; ++t) {
        const int kb = t * 64;

        // ---- issue ALL loads first (K -> V -> M); compiler's per-use vmcnt
        //      leaves V/M outstanding through GEMM1
        s16x8 kf[4][2];
#pragma unroll
        for (int cf = 0; cf < 4; ++cf) {
            int krow = imin(kb + cf * 16 + lm, Lq - 1);   // clamp: m=0 kills k>576
            const unsigned short* kp = KpBH + (size_t)krow * (NH * DD);
            kf[cf][0] = *(const s16x8*)kp;
            kf[cf][1] = *(const s16x8*)(kp + 32);
        }
        s16x8 vf[2][4];
#pragma unroll
        for (int ks = 0; ks < 2; ++ks)
#pragma unroll
            for (int df = 0; df < 4; ++df)
                vf[ks][df] = *(const s16x8*)(VtD[df] + kb + ks * 32);
        uint2 mu[4];
#pragma unroll
        for (int cf = 0; cf < 4; ++cf)
            mu[cf] = *(const uint2*)(Mw + t * 1024 + cf * 256);

        // ---- GEMM1 (transposed): S^T[64k x 16q] = K' · Q^T
        f32x4 sf[4];
#pragma unroll
        for (int cf = 0; cf < 4; ++cf) {
            f32x4 acc = {};
            acc = __builtin_amdgcn_mfma_f32_16x16x32_bf16(kf[cf][0], a_q[0], acc, 0, 0, 0);
            acc = __builtin_amdgcn_mfma_f32_16x16x32_bf16(kf[cf][1], a_q[1], acc, 0, 0, 0);
            sf[cf] = acc;   // reg r: k_local = cf*16 + g*4 + r, q = q0w + lm
        }

        // ---- p = max(s,0)*m + eps; row-sum; pack 4 -> b64 wave-private LDS
#pragma unroll
        for (int cf = 0; cf < 4; ++cf) {
            float m0 = bflo(mu[cf].x), m1 = bfhi(mu[cf].x);
            float m2 = bflo(mu[cf].y), m3 = bfhi(mu[cf].y);
            float p0 = fmaf(fmaxf(sf[cf][0], 0.0f), m0, EPSf);
            float p1 = fmaf(fmaxf(sf[cf][1], 0.0f), m1, EPSf);
            float p2 = fmaf(fmaxf(sf[cf][2], 0.0f), m2, EPSf);
            float p3 = fmaf(fmaxf(sf[cf][3], 0.0f), m3, EPSf);
            rs += (p0 + p1) + (p2 + p3);
            unsigned int d0 = f2bf(p0) | (f2bf(p1) << 16);
            unsigned int d1 = f2bf(p2) | (f2bf(p3) << 16);
            *(uint2*)&s_pw[lm * 72 + cf * 16 + g * 4] = make_uint2(d0, d1);
        }
        // no barrier: s_pw wave-private; same-wave LDS RAW ordered by lgkmcnt

        // ---- GEMM2: O[16q x 64d] += P · V
#pragma unroll
        for (int ks = 0; ks < 2; ++ks) {
            s16x8 pa = *(const s16x8*)&s_pw[lm * 72 + ks * 32 + g * 8];
#pragma unroll
            for (int df = 0; df < 4; ++df)
                o_acc[df] = __builtin_amdgcn_mfma_f32_16x16x32_bf16(pa, vf[ks][df],
                                                                    o_acc[df], 0, 0, 0);
        }
    }
    // k in [577,640): m=0, V^T=0 -> only +63*eps on rs (negligible)

    // ---- total row sum for q = q0w+lm: combine the 4 quad partials
    float tot = rs;
    tot += __shfl_xor(tot, 16, 64);
    tot += __shfl_xor(tot, 32, 64);
    float inv = (tot > 0.0f) ? 1.0f / tot : 0.0f;

    // ---- epilogue: rows q = q0w + g*4 + r; fetch inv from lane (g*4+r)
#pragma unroll
    for (int r = 0; r < 4; ++r) {
        int   qrow  = q0w + g * 4 + r;
        float inv_r = __shfl(inv, g * 4 + r, 64);
        if (qrow < Lq) {
            size_t base = ((size_t)((b * Lq + qrow) * NH + h)) * DD;
#pragma unroll
            for (int df = 0; df < 4; ++df) {
                float val = o_acc[df][r] * inv_r;
                if constexpr (F32)
                    ((float*)Og)[base + df * 16 + lm] = val;
                else
                    ((unsigned short*)Og)[base + df * 16 + lm] = (unsigned short)f2bf(val);
            }
        }
    }
}

__global__ __launch_bounds__(256, 3)
void fused_topo_attn(const void* __restrict__ Qg,
                     const unsigned short* __restrict__ Kp,
                     const unsigned short* __restrict__ Vt,
                     const unsigned short* __restrict__ M2,
                     void* __restrict__ Og) {
    // only the P round-trip lives in LDS now: 9216 B
    __shared__ __align__(16) unsigned short s_p[4 * 16 * 72];

    if (probe_f32(Qg)) attn_body<true>(Qg, Kp, Vt, M2, Og, s_p);
    else               attn_body<false>(Qg, Kp, Vt, M2, Og, s_p);
}

extern "C" void kernel_launch(void* const* d_in, const int* in_sizes, int n_in,
                              void* d_out, int out_size, void* d_ws, size_t ws_size,
                              hipStream_t stream) {
    (void)in_sizes; (void)n_in; (void)out_size; (void)ws_size;
    unsigned short* Kp = (unsigned short*)d_ws;
    unsigned short* Vt = (unsigned short*)((char*)d_ws + VT_OFF);
    unsigned short* M2 = (unsigned short*)((char*)d_ws + M2_OFF);

    prep_all<<<KBLK + VBLK + MBLK, 256, 0, stream>>>(
        d_in[0], d_in[1], d_in[2], d_in[3], Kp, Vt, M2);
    fused_topo_attn<<<960, 256, 0, stream>>>(d_in[0], Kp, Vt, M2, d_out);
}

// Round 7
// 123.592 us; speedup vs baseline: 1.4031x; 1.4031x over previous
//
#include <hip/hip_runtime.h>

// Fused kernelized attention w/ Toeplitz topological mask, MI355X gfx950.
// B=8 H=12 L=577 (24x24 grid + CLS) D=64, fp32 I/O (runtime-probed vs bf16).
//
// out[b,q,h,:] = sum_k p(q,k) v[k,:] / sum_k p(q,k)
//   p = (relu(q)/8+eps)·(relu(k)+eps) * |mask(h,q,k)| + eps
//
// R7: 32 q per WAVE (two A-frag q-sets sharing every K/V LDS fragment read:
// LDS data-ops per unit work drop 22 -> 14), 128-thread blocks (2 waves,
// 64 q), grid 960 all-resident at exactly 40 KB LDS (dbuf K/V + swizzled
// stride-64 P). Single barrier per k-tile; stage(t+1) issued right after
// the barrier; M=|mask| prefetched into registers from lane-ordered M2.

#define Lq 577
#define NH 12
#define NB 8
#define DD 64
#define PAR 2304
#define EPSf 1e-8f

// workspace layout (bytes)
#define VT_OFF 7090176ull     // K' = 3,545,088 elem * 2B  [b,k,h,d]
#define M2_OFF 14954496ull    // + V^T = 8*12*64*640*2 = 7,864,320
                              // + M2  = 12*40*10*4*64*4*2 = 9,830,400 (24.8 MB)

// prep grid sections
#define KBLK 1731             // K': 1731*256*8 = 3,545,088 elems
#define VBLK 960              // V^T: 10 kt x 12 h x 8 b
#define MBLK 480              // M2: 40 qg x 12 h

typedef __attribute__((ext_vector_type(4))) float f32x4;
typedef __attribute__((ext_vector_type(8))) short s16x8;

__device__ __forceinline__ float bflo(unsigned int u) {
    return __builtin_bit_cast(float, u << 16);
}
__device__ __forceinline__ float bfhi(unsigned int u) {
    return __builtin_bit_cast(float, u & 0xffff0000u);
}
// float -> bf16 round-to-nearest-even
__device__ __forceinline__ unsigned int f2bf(float f) {
    unsigned int x = __builtin_bit_cast(unsigned int, f);
    return (x + 0x7fffu + ((x >> 16) & 1u)) >> 16;
}
__device__ __forceinline__ int imin(int a, int b) { return a < b ? a : b; }

// async global->LDS, 16B per lane; lds dest = wave-uniform base + lane*16
__device__ __forceinline__ void gload_lds16(const unsigned short* g, unsigned short* l) {
    __builtin_amdgcn_global_load_lds(
        (const __attribute__((address_space(1))) unsigned int*)g,
        (__attribute__((address_space(3))) unsigned int*)l, 16, 0, 0);
}

// per-wave dtype probe: fp32 N(0,1) lands in (2^-12, 64); bf16-pair
// reinterpretation lands at ~2^+-100 / denormal. Works for partial waves.
__device__ __forceinline__ bool probe_f32(const void* Qg) {
    float x = fabsf(((const float*)Qg)[threadIdx.x]);
    unsigned long long hit = __ballot(x > 2.44140625e-4f && x < 64.0f);
    unsigned long long act = __ballot(1);
    return 2 * __popcll(hit) >= __popcll(act);
}

// 8 consecutive elements -> float, dtype-templated
template <bool F32>
__device__ __forceinline__ void load8f(const void* G, size_t eidx, float* o) {
    if constexpr (F32) {
        const float* p = (const float*)G + eidx;
        float4 a = *(const float4*)p;
        float4 b = *(const float4*)(p + 4);
        o[0] = a.x; o[1] = a.y; o[2] = a.z; o[3] = a.w;
        o[4] = b.x; o[5] = b.y; o[6] = b.z; o[7] = b.w;
    } else {
        const unsigned short* p = (const unsigned short*)G + eidx;
        uint4 a = *(const uint4*)p;
        unsigned int u[4] = {a.x, a.y, a.z, a.w};
#pragma unroll
        for (int j = 0; j < 4; ++j) {
            o[2 * j]     = bflo(u[j]);
            o[2 * j + 1] = bfhi(u[j]);
        }
    }
}

// ---------------- fused prep: K' | V^T | M2 by grid section
template <bool F32>
__device__ void prep_k_body(const void* Kg, unsigned short* Kp, int bx) {
    size_t i8 = ((size_t)bx * 256 + threadIdx.x) * 8;
    float f[8];
    load8f<F32>(Kg, i8, f);
    unsigned int o[4];
#pragma unroll
    for (int j = 0; j < 4; ++j) {
        unsigned int lo = f2bf(fmaxf(f[2 * j], 0.0f) + EPSf);
        unsigned int hi = f2bf(fmaxf(f[2 * j + 1], 0.0f) + EPSf);
        o[j] = lo | (hi << 16);
    }
    *(uint4*)(Kp + i8) = make_uint4(o[0], o[1], o[2], o[3]);
}

template <bool F32>
__device__ void prep_vt_body(const void* Vg, unsigned short* Vt,
                             unsigned short* s, int id) {
    const int t  = threadIdx.x;
    const int kt = id % 10;
    const int h  = (id / 10) % NH;
    const int b  = id / 120;
    {
        int kl  = t >> 2;              // 0..63
        int dch = (t & 3) * 16;
        int k   = kt * 64 + kl;
        unsigned int pk[8] = {};
        if (k <= 576) {
            float f[16];
            size_t base = ((size_t)((b * Lq + k) * NH + h)) * DD + dch;
            load8f<F32>(Vg, base, f);
            load8f<F32>(Vg, base + 8, f + 8);
#pragma unroll
            for (int j = 0; j < 8; ++j) {
                float a0 = f[2 * j], a1 = f[2 * j + 1];
                a0 = (a0 == a0) ? a0 : 0.0f;
                a1 = (a1 == a1) ? a1 : 0.0f;
                pk[j] = f2bf(a0) | (f2bf(a1) << 16);
            }
        }
#pragma unroll
        for (int j = 0; j < 8; ++j)
            *(unsigned int*)&s[kl * 72 + dch + 2 * j] = pk[j];
    }
    __syncthreads();
    {
        int d   = t >> 2;
        int kch = (t & 3) * 16;
        unsigned int o[8];
#pragma unroll
        for (int j = 0; j < 8; ++j) {
            unsigned short v0 = s[(kch + 2 * j) * 72 + d];
            unsigned short v1 = s[(kch + 2 * j + 1) * 72 + d];
            o[j] = (unsigned int)v0 | ((unsigned int)v1 << 16);
        }
        size_t base = ((size_t)((b * NH + h) * 64 + d)) * 640 + kt * 64 + kch;
        *(uint4*)(Vt + base)     = make_uint4(o[0], o[1], o[2], o[3]);
        *(uint4*)(Vt + base + 8) = make_uint4(o[4], o[5], o[6], o[7]);
    }
}

// M2[h][qg][kt][cf][lane] quads of bf16: lane (lm=lane&15, g=lane>>4) holds
// |mask| for q = qg*16+lm, k = kt*64 + cf*16 + g*4 + {0..3}
template <bool F32>
__device__ void prep_m2_body(const void* Tg, unsigned short* M2, int id) {
    const int qg = id % 40;
    const int h  = id / 40;
    const int t    = threadIdx.x;
    const int cf   = t >> 6;
    const int lane = t & 63;
    const int lm   = lane & 15;
    const int g    = lane >> 4;
    const int q    = qg * 16 + lm;
    const bool qok = q < Lq;
    int cq = 0;
    if (qok && q > 0) {
        int qq = q - 1;
        int qi = (qq * 2731) >> 16;       // floor(qq/24)
        cq = qq + 24 * qi + 1176;
    }
    for (int kt = 0; kt < 10; ++kt) {
        unsigned int hv[4];
#pragma unroll
        for (int e = 0; e < 4; ++e) {
            int k = kt * 64 + cf * 16 + g * 4 + e;
            float m;
            if (!qok || k > 576) m = 0.0f;
            else if (k == 0 || q == 0) m = 1.0f;
            else {
                int kk = k - 1;
                int ki = (kk * 2731) >> 16;
                int idx = cq - (kk + 24 * ki);
                float pv = F32 ? ((const float*)Tg)[h * PAR + idx]
                               : bflo((unsigned int)((const unsigned short*)Tg)[h * PAR + idx]);
                m = fabsf(pv);
                m = (m == m) ? m : 0.0f;
            }
            hv[e] = f2bf(m);
        }
        size_t base = ((size_t)(((h * 40 + qg) * 10 + kt) * 4 + cf) * 64 + lane) * 4;
        *(uint2*)(M2 + base) = make_uint2(hv[0] | (hv[1] << 16), hv[2] | (hv[3] << 16));
    }
}

__global__ __launch_bounds__(256)
void prep_all(const void* __restrict__ Qg, const void* __restrict__ Kg,
              const void* __restrict__ Vg, const void* __restrict__ Tg,
              unsigned short* __restrict__ Kp, unsigned short* __restrict__ Vt,
              unsigned short* __restrict__ M2) {
    __shared__ unsigned short s[64 * 72];
    bool f32 = probe_f32(Qg);
    int bx = blockIdx.x;
    if (bx < KBLK) {
        if (f32) prep_k_body<true>(Kg, Kp, bx);
        else     prep_k_body<false>(Kg, Kp, bx);
    } else if (bx < KBLK + VBLK) {
        if (f32) prep_vt_body<true>(Vg, Vt, s, bx - KBLK);
        else     prep_vt_body<false>(Vg, Vt, s, bx - KBLK);
    } else {
        if (f32) prep_m2_body<true>(Tg, M2, bx - KBLK - VBLK);
        else     prep_m2_body<false>(Tg, M2, bx - KBLK - VBLK);
    }
}

// ---------------- main kernel: 128 thr (2 waves), 32 q per wave
template <bool F32>
__device__ void attn_body(const void* __restrict__ Qg,
                          const unsigned short* __restrict__ Kp,
                          const unsigned short* __restrict__ Vt,
                          const unsigned short* __restrict__ M2,
                          void* __restrict__ Og,
                          unsigned short* s_k, unsigned short* s_vt,
                          unsigned short* s_p) {
    const int tid  = threadIdx.x;
    const int w    = tid >> 6;
    const int lane = tid & 63;
    const int g    = lane >> 4;   // quad
    const int lm   = lane & 15;

    // XCD swizzle: blocks sharing (b,h) are 96 apart (96 % 8 == 0 -> same XCD)
    const int bid = blockIdx.x;
    const int qt  = bid / 96;     // q tile (64 rows), 0..9
    const int bh  = bid - qt * 96;
    const int h   = bh % NH;
    const int b   = bh / NH;

    unsigned short* s_pw = s_p + w * 2048;   // wave-private P tile [32][64] swizzled

    const int q0w = qt * 64 + w * 32;   // wave's first q row (2 sets of 16)

    // ---- Q B-frags for both q-sets: lane holds Q[q0w+s*16+lm][ds*32+g*8+j]
    s16x8 a_q[2][2];
#pragma unroll
    for (int s = 0; s < 2; ++s) {
        int qc = imin(q0w + s * 16 + lm, Lq - 1);
        size_t rbase = ((size_t)((b * Lq + qc) * NH + h)) * DD;
#pragma unroll
        for (int ds = 0; ds < 2; ++ds) {
            float f[8];
            load8f<F32>(Qg, rbase + ds * 32 + g * 8, f);
            s16x8 a;
#pragma unroll
            for (int j = 0; j < 8; ++j) {
                float v = fmaf(fmaxf(f[j], 0.0f), 0.125f, EPSf);  // relu/8+eps
                a[j] = (short)f2bf(v);
            }
            a_q[s][ds] = a;
        }
    }

    // ---- staging lane constants (16B XOR swizzle on global source chunks)
    const int r8 = lane >> 3;          // row within 8-row group
    const int c8 = lane & 7;           // 16B physical chunk within row
    const int xr = (c8 ^ r8) * 8;      // logical element offset of lane's chunk
    const int x7 = lm & 7;             // fragment-read swizzle key

    const unsigned short* KpBH = Kp + (size_t)b * (Lq * NH * DD) + h * DD;  // +k*768
    const unsigned short* VtBH = Vt + (size_t)(b * NH + h) * 64 * 640;      // +d*640
    const unsigned short* Mw0  = M2 + (size_t)(h * 40 + qt * 4 + w * 2) * 10240 + lane * 4;
    const unsigned short* Mw1  = Mw0 + 10240;

    f32x4 o_acc[2][4] = {};  // [set][df]: rows q_local=g*4+r, cols d=df*16+lm
    float rs[2] = {};        // per-lane partial row sums (q = q0w+s*16+lm)

    uint2 mcur[2][4], mnxt[2][4];

    // stage tile t into LDS buffer `buf`: wave stages 32 K-rows + 32 V^T-rows
    auto stage = [&](int t, int buf) {
        int kbn = t * 64;
#pragma unroll
        for (int i = 0; i < 4; ++i) {
            int krow = imin(kbn + w * 32 + i * 8 + r8, Lq - 1);
            int drow = w * 32 + i * 8 + r8;
            unsigned short* kd = s_k  + buf * 4096 + (w * 32 + i * 8) * 64;
            unsigned short* vd = s_vt + buf * 4096 + (w * 32 + i * 8) * 64;
            gload_lds16(KpBH + (size_t)krow * (NH * DD) + xr, kd);
            gload_lds16(VtBH + (size_t)drow * 640 + kbn + xr, vd);
        }
    };

    // prologue: tile 0 in flight
    stage(0, 0);
#pragma unroll
    for (int cf = 0; cf < 4; ++cf) {
        mcur[0][cf] = *(const uint2*)(Mw0 + cf * 256);
        mcur[1][cf] = *(const uint2*)(Mw1 + cf * 256);
    }

#pragma unroll 2
    for (int t = 0; t < 10; ++t) {
        const int cur = t & 1;
        __syncthreads();   // drains vmcnt: tile t staged; buf cur^1 free

        if (t < 9) {
            stage(t + 1, cur ^ 1);     // overlaps with tile-t compute below
#pragma unroll
            for (int cf = 0; cf < 4; ++cf) {
                mnxt[0][cf] = *(const uint2*)(Mw0 + (t + 1) * 1024 + cf * 256);
                mnxt[1][cf] = *(const uint2*)(Mw1 + (t + 1) * 1024 + cf * 256);
            }
        }

        const unsigned short* skb = s_k  + cur * 4096;
        const unsigned short* svb = s_vt + cur * 4096;

        // ---- GEMM1 (transposed): S^T[64k x 32q] = K' · Q^T, kf shared by sets
        f32x4 sf[2][4];
#pragma unroll
        for (int cf = 0; cf < 4; ++cf) {
            const unsigned short* skr = skb + (cf * 16 + lm) * 64;
            int co = (g ^ x7) * 8;
            s16x8 kf0 = *(const s16x8*)(skr + co);
            s16x8 kf1 = *(const s16x8*)(skr + (co ^ 32));
#pragma unroll
            for (int s = 0; s < 2; ++s) {
                f32x4 acc = {};
                acc = __builtin_amdgcn_mfma_f32_16x16x32_bf16(kf0, a_q[s][0], acc, 0, 0, 0);
                acc = __builtin_amdgcn_mfma_f32_16x16x32_bf16(kf1, a_q[s][1], acc, 0, 0, 0);
                sf[s][cf] = acc;   // reg r: k_local = cf*16+g*4+r, q = q0w+s*16+lm
            }
        }

        // ---- p = max(s,0)*m + eps; row-sum; pack 4 -> b64 wave-private LDS
        //      P layout: row = s*16+lm (stride 64), chunk swizzled by lm&7
#pragma unroll
        for (int s = 0; s < 2; ++s)
#pragma unroll
            for (int cf = 0; cf < 4; ++cf) {
                float m0 = bflo(mcur[s][cf].x), m1 = bfhi(mcur[s][cf].x);
                float m2 = bflo(mcur[s][cf].y), m3 = bfhi(mcur[s][cf].y);
                float p0 = fmaf(fmaxf(sf[s][cf][0], 0.0f), m0, EPSf);
                float p1 = fmaf(fmaxf(sf[s][cf][1], 0.0f), m1, EPSf);
                float p2 = fmaf(fmaxf(sf[s][cf][2], 0.0f), m2, EPSf);
                float p3 = fmaf(fmaxf(sf[s][cf][3], 0.0f), m3, EPSf);
                rs[s] += (p0 + p1) + (p2 + p3);
                unsigned int d0 = f2bf(p0) | (f2bf(p1) << 16);
                unsigned int d1 = f2bf(p2) | (f2bf(p3) << 16);
                int col = ((cf * 2 + (g >> 1)) ^ x7) * 8 + (g & 1) * 4;
                *(uint2*)&s_pw[(s * 16 + lm) * 64 + col] = make_uint2(d0, d1);
            }
        // no barrier: s_pw wave-private; same-wave LDS RAW ordered by lgkmcnt

        // ---- GEMM2: O[32q x 64d] += P · V, vb shared by sets
#pragma unroll
        for (int ks = 0; ks < 2; ++ks) {
            s16x8 pa[2];
#pragma unroll
            for (int s = 0; s < 2; ++s)
                pa[s] = *(const s16x8*)&s_pw[(s * 16 + lm) * 64 + ((ks * 4 + g) ^ x7) * 8];
#pragma unroll
            for (int df = 0; df < 4; ++df) {
                const unsigned short* svr = svb + (df * 16 + lm) * 64;
                s16x8 vb = *(const s16x8*)(svr + ((ks * 4 + g) ^ x7) * 8);
                o_acc[0][df] = __builtin_amdgcn_mfma_f32_16x16x32_bf16(pa[0], vb, o_acc[0][df], 0, 0, 0);
                o_acc[1][df] = __builtin_amdgcn_mfma_f32_16x16x32_bf16(pa[1], vb, o_acc[1][df], 0, 0, 0);
            }
        }

#pragma unroll
        for (int s = 0; s < 2; ++s)
#pragma unroll
            for (int cf = 0; cf < 4; ++cf) mcur[s][cf] = mnxt[s][cf];
    }
    // k in [577,640): m=0, V^T=0 -> only +63*eps on rs (negligible)

    // ---- epilogue per q-set
#pragma unroll
    for (int s = 0; s < 2; ++s) {
        float tot = rs[s];
        tot += __shfl_xor(tot, 16, 64);
        tot += __shfl_xor(tot, 32, 64);
        float inv = (tot > 0.0f) ? 1.0f / tot : 0.0f;
#pragma unroll
        for (int r = 0; r < 4; ++r) {
            int   qrow  = q0w + s * 16 + g * 4 + r;
            float inv_r = __shfl(inv, g * 4 + r, 64);
            if (qrow < Lq) {
                size_t base = ((size_t)((b * Lq + qrow) * NH + h)) * DD;
#pragma unroll
                for (int df = 0; df < 4; ++df) {
                    float val = o_acc[s][df][r] * inv_r;
                    if constexpr (F32)
                        ((float*)Og)[base + df * 16 + lm] = val;
                    else
                        ((unsigned short*)Og)[base + df * 16 + lm] = (unsigned short)f2bf(val);
                }
            }
        }
    }
}

__global__ __launch_bounds__(128, 2)
void fused_topo_attn(const void* __restrict__ Qg,
                     const unsigned short* __restrict__ Kp,
                     const unsigned short* __restrict__ Vt,
                     const unsigned short* __restrict__ M2,
                     void* __restrict__ Og) {
    // exactly 40,960 B -> 4 blocks/CU (160 KB), grid 960 all-resident
    __shared__ __align__(16) unsigned short s_k[2 * 64 * 64];   // 16384 B dbuf
    __shared__ __align__(16) unsigned short s_vt[2 * 64 * 64];  // 16384 B dbuf
    __shared__ __align__(16) unsigned short s_p[2 * 32 * 64];   //  8192 B swizzled

    if (probe_f32(Qg)) attn_body<true>(Qg, Kp, Vt, M2, Og, s_k, s_vt, s_p);
    else               attn_body<false>(Qg, Kp, Vt, M2, Og, s_k, s_vt, s_p);
}

extern "C" void kernel_launch(void* const* d_in, const int* in_sizes, int n_in,
                              void* d_out, int out_size, void* d_ws, size_t ws_size,
                              hipStream_t stream) {
    (void)in_sizes; (void)n_in; (void)out_size; (void)ws_size;
    unsigned short* Kp = (unsigned short*)d_ws;
    unsigned short* Vt = (unsigned short*)((char*)d_ws + VT_OFF);
    unsigned short* M2 = (unsigned short*)((char*)d_ws + M2_OFF);

    prep_all<<<KBLK + VBLK + MBLK, 256, 0, stream>>>(
        d_in[0], d_in[1], d_in[2], d_in[3], Kp, Vt, M2);
    fused_topo_attn<<<960, 128, 0, stream>>>(d_in[0], Kp, Vt, M2, d_out);
}